// Round 1
// baseline (39.868 us; speedup 1.0000x reference)
//
#include <hip/hip_runtime.h>
#include <math.h>

// Problem constants (from setup_inputs)
#define B_  16
#define A_  3
#define H_  76
#define W_  76
#define C_  80
#define T_  32
#define N_TGT (B_*T_)            // 512
#define CELLS (B_*A_*H_*W_)      // 277248
#define NBLK_C (CELLS/256)       // 1083 (exact)
#define IGNORE_THRES_ 0.5f
#define EPS_BCE_ 1e-7f

__device__ __forceinline__ float sigmoidf_(float z) { return 1.0f / (1.0f + expf(-z)); }
__device__ __forceinline__ float smooth_l1_(float d) {
    d = fabsf(d);
    return (d < 1.0f) ? 0.5f * d * d : d - 0.5f;
}

// ---------------------------------------------------------------------------
// Kernel T: one block, 512 threads (one per target).
//  - per-target: decode gt box, anchor IoU, best anchor
//  - scatter mask / conf_zero bits into flag map (atomicOr; order-free)
//  - last-write-wins winner detection via shared-mem key comparison
//  - gathered losses (x,y,w,h, obj BCE, class CE) for winners
//  - n_correct over ALL targets (duplicates included, per reference)
//  - deterministic reduction (shuffle tree + fixed-order wave combine)
// acc layout: [0..3]=sum lx,ly,lw,lh  [4]=sum obj bce  [5]=sum ce
//             [6]=nM (winner count)   [7]=n_correct
// ---------------------------------------------------------------------------
__global__ __launch_bounds__(512) void ktargets(
    const float* __restrict__ xreg, const float* __restrict__ xcls,
    const float* __restrict__ tgt, const float* __restrict__ anch,
    float* __restrict__ acc, unsigned int* __restrict__ flags)
{
    __shared__ int s_key[N_TGT];
    __shared__ float s_red[8 * 8];  // 8 waves x 8 quantities

    const int t = threadIdx.x;           // 0..511 == global target index
    const int b = t >> 5;                // /32
    const float* tp = tgt + t * 5;

    float gx = tp[0] * (float)W_;
    float gy = tp[1] * (float)H_;
    float gw = tp[2] * (float)W_;
    float gh = tp[3] * (float)H_;
    int cls = (int)tp[4];

    int gi = (int)floorf(gx); gi = min(max(gi, 0), W_ - 1);
    int gj = (int)floorf(gy); gj = min(max(gj, 0), H_ - 1);

    float aw0 = anch[0], ah0 = anch[1];
    float aw1 = anch[2], ah1 = anch[3];
    float aw2 = anch[4], ah2 = anch[5];

    float area = gw * gh;
    float iou0, iou1, iou2;
    {
        float i0 = fminf(gw, aw0) * fminf(gh, ah0);
        iou0 = i0 / (area + aw0 * ah0 - i0 + 1e-16f);
        float i1 = fminf(gw, aw1) * fminf(gh, ah1);
        iou1 = i1 / (area + aw1 * ah1 - i1 + 1e-16f);
        float i2 = fminf(gw, aw2) * fminf(gh, ah2);
        iou2 = i2 / (area + aw2 * ah2 - i2 + 1e-16f);
    }
    // first-max argmax (matches jnp.argmax tiebreak)
    int best = 0; float bi = iou0;
    if (iou1 > bi) { best = 1; bi = iou1; }
    if (iou2 > bi) { best = 2; bi = iou2; }

    // scatter flag bits: bit0 = mask (at best anchor), bit1 = conf_zero (iou>thr)
    float ious[3] = { iou0, iou1, iou2 };
    #pragma unroll
    for (int a = 0; a < A_; ++a) {
        unsigned int bits = 0;
        if (a == best) bits |= 1u;
        if (ious[a] > IGNORE_THRES_) bits |= 2u;
        if (bits) {
            int cell = ((b * A_ + a) * H_ + gj) * W_ + gi;
            atomicOr(&flags[cell >> 2], bits << ((cell & 3) * 8));
        }
    }

    // last-write-wins: target t is the winner iff no later target (same b)
    // hits the same (best, gj, gi)
    s_key[t] = (best * H_ + gj) * W_ + gi;
    __syncthreads();
    bool winner = true;
    {
        int mykey = s_key[t];
        int hi = (b + 1) * T_;
        for (int u = t + 1; u < hi; ++u)
            if (s_key[u] == mykey) { winner = false; break; }
    }

    // gather predictions at the matched cell
    int cell_best = ((b * A_ + best) * H_ + gj) * W_ + gi;
    const float* rp = xreg + (size_t)cell_best * 5;
    float rx = rp[0], ry = rp[1], rw = rp[2], rh = rp[3], rc = rp[4];

    // online max/argmax/logsumexp over the 80-class row
    const float* cp = xcls + (size_t)cell_best * C_;
    float m = -INFINITY, sum = 0.0f; int am = 0;
    for (int c = 0; c < C_; ++c) {
        float v = cp[c];
        if (v > m) { sum = sum * expf(m - v) + 1.0f; m = v; am = c; }
        else       { sum += expf(v - m); }
    }
    float lse = m + logf(sum);

    bool correct = (am == cls) && (rc > 0.0f);  // sigmoid(rc)>0.5 <=> rc>0

    float wlx = 0, wly = 0, wlw = 0, wlh = 0, wobj = 0, wce = 0, wm = 0;
    if (winner) {
        float tx = gx - (float)gi;
        float ty = gy - (float)gj;
        float aw = (best == 0) ? aw0 : ((best == 1) ? aw1 : aw2);
        float ah = (best == 0) ? ah0 : ((best == 1) ? ah1 : ah2);
        float tw = logf(gw / aw + 1e-16f);
        float th = logf(gh / ah + 1e-16f);
        wlx = smooth_l1_(sigmoidf_(rx) - tx);
        wly = smooth_l1_(sigmoidf_(ry) - ty);
        wlw = smooth_l1_(rw - tw);
        wlh = smooth_l1_(rh - th);
        float pc = sigmoidf_(rc);
        pc = fminf(fmaxf(pc, EPS_BCE_), 1.0f - EPS_BCE_);
        wobj = -logf(pc);
        wce = lse - cp[cls];
        wm = 1.0f;
    }

    // deterministic reduction: shuffle tree within each 64-lane wave,
    // then thread 0 combines the 8 wave partials in fixed order
    float vals[8] = { wlx, wly, wlw, wlh, wobj, wce, wm, correct ? 1.0f : 0.0f };
    #pragma unroll
    for (int k = 0; k < 8; ++k) {
        float v = vals[k];
        #pragma unroll
        for (int off = 32; off > 0; off >>= 1) v += __shfl_down(v, off, 64);
        vals[k] = v;
    }
    int lane = t & 63, w = t >> 6;
    if (lane == 0) {
        #pragma unroll
        for (int k = 0; k < 8; ++k) s_red[w * 8 + k] = vals[k];
    }
    __syncthreads();
    if (t == 0) {
        #pragma unroll
        for (int k = 0; k < 8; ++k) {
            float s = 0.0f;
            for (int wv = 0; wv < 8; ++wv) s += s_red[wv * 8 + k];
            acc[k] = s;
        }
    }
}

// ---------------------------------------------------------------------------
// Kernel C: noobj BCE over all cells. One cell per thread, exact grid.
// conf_false cell <=> flag byte == 0. Per-block deterministic partials.
// ---------------------------------------------------------------------------
__global__ __launch_bounds__(256) void knoobj(
    const float* __restrict__ xreg, const unsigned char* __restrict__ flags,
    float* __restrict__ pn, float* __restrict__ pf)
{
    int cell = blockIdx.x * 256 + threadIdx.x;
    unsigned char f = flags[cell];
    float z = xreg[(size_t)cell * 5 + 4];
    float term = 0.0f, cnt = 0.0f;
    if (f == 0) {
        float pc = sigmoidf_(z);
        pc = fminf(fmaxf(pc, EPS_BCE_), 1.0f - EPS_BCE_);
        term = -logf(1.0f - pc);
        cnt = 1.0f;
    }
    #pragma unroll
    for (int off = 32; off > 0; off >>= 1) {
        term += __shfl_down(term, off, 64);
        cnt  += __shfl_down(cnt,  off, 64);
    }
    __shared__ float s[8];
    int lane = threadIdx.x & 63, w = threadIdx.x >> 6;
    if (lane == 0) { s[w] = term; s[4 + w] = cnt; }
    __syncthreads();
    if (threadIdx.x == 0) {
        pn[blockIdx.x] = s[0] + s[1] + s[2] + s[3];
        pf[blockIdx.x] = s[4] + s[5] + s[6] + s[7];
    }
}

// ---------------------------------------------------------------------------
// Kernel F: deterministic final sum of block partials + combine -> 5 outputs
// ---------------------------------------------------------------------------
__global__ __launch_bounds__(256) void kfinal(
    const float* __restrict__ pn, const float* __restrict__ pf,
    const float* __restrict__ acc, float* __restrict__ out)
{
    float sn = 0.0f, sf = 0.0f;
    for (int i = threadIdx.x; i < NBLK_C; i += 256) { sn += pn[i]; sf += pf[i]; }
    #pragma unroll
    for (int off = 32; off > 0; off >>= 1) {
        sn += __shfl_down(sn, off, 64);
        sf += __shfl_down(sf, off, 64);
    }
    __shared__ float s[8];
    int lane = threadIdx.x & 63, w = threadIdx.x >> 6;
    if (lane == 0) { s[w] = sn; s[4 + w] = sf; }
    __syncthreads();
    if (threadIdx.x == 0) {
        sn = s[0] + s[1] + s[2] + s[3];
        sf = s[4] + s[5] + s[6] + s[7];
        float nM = fmaxf(acc[6], 1.0f);
        float nF = fmaxf(sf, 1.0f);
        float lx = acc[0] / nM, ly = acc[1] / nM;
        float lw = acc[2] / nM, lh = acc[3] / nM;
        float lconf = sn / nF + acc[4] / nM;  // NOOBJ_SCALE=OBJ_SCALE=1
        float lcls = acc[5] / nM;             // CLASS_SCALE=1
        float coord = lx + ly + lw + lh;      // COORD_SCALE=1
        out[0] = coord + lconf + lcls;
        out[1] = coord;
        out[2] = lconf;
        out[3] = lcls;
        out[4] = acc[7];                      // n_correct (float32 buffer)
    }
}

extern "C" void kernel_launch(void* const* d_in, const int* in_sizes, int n_in,
                              void* d_out, int out_size, void* d_ws, size_t ws_size,
                              hipStream_t stream) {
    const float* xreg = (const float*)d_in[0];
    const float* xcls = (const float*)d_in[1];
    const float* tgt  = (const float*)d_in[2];
    const float* anch = (const float*)d_in[3];
    float* out = (float*)d_out;

    char* ws = (char*)d_ws;
    float* acc = (float*)ws;                          // 16 floats reserved
    float* pn  = (float*)(ws + 64);                   // NBLK_C floats
    float* pf  = (float*)(ws + 64 + 4352);            // NBLK_C floats
    unsigned char* flags = (unsigned char*)(ws + 16384);  // CELLS bytes

    // flags must be zeroed every call (harness poisons ws once, never restores)
    hipMemsetAsync(flags, 0, CELLS, stream);

    ktargets<<<1, 512, 0, stream>>>(xreg, xcls, tgt, anch, acc, (unsigned int*)flags);
    knoobj<<<NBLK_C, 256, 0, stream>>>(xreg, flags, pn, pf);
    kfinal<<<1, 256, 0, stream>>>(pn, pf, acc, out);
}